// Round 7
// baseline (1379.738 us; speedup 1.0000x reference)
//
#include <hip/hip_runtime.h>
#include <hip/hip_bf16.h>

#define NN    8192
#define FF    64
#define HH    64
#define DD    64
#define TOPK  15
#define CHUNKS 16
#define CCOLS (NN / CHUNKS)      // 512 cols per chunk
#define CTILES (CCOLS / 64)      // 8 col-tiles per chunk
#define PCK   20                 // per-chunk approx candidates
#define RK    24                 // rescored candidates per row

typedef __attribute__((ext_vector_type(8))) short bf16x8;  // 8 bf16 = 4 VGPR
typedef __attribute__((ext_vector_type(4))) float f32x4;

// Sorted-descending top-K insert, tie-break (value desc, index asc) ==
// jax.lax.top_k semantics; order-independent due to explicit index tie-break.
template<int K, typename T>
__device__ __forceinline__ void topk_insert(T (&tv)[K], int (&ti)[K], T v, int j)
{
    T nv = v; int nj = j;
#pragma unroll
    for (int k = 0; k < K; ++k) {
        bool sw = (nv > tv[k]) || ((nv == tv[k]) && (nj < ti[k]));
        T otv = tv[k]; int oti = ti[k];
        tv[k] = sw ? nv : otv;  ti[k] = sw ? nj : oti;
        nv = sw ? otv : nv;     nj = sw ? oti : nj;
    }
}

// K1: per-node 2-layer MLP (wave per node, lane = unit), computed in FP64 so
// the final index-determining rescore can match the harness's np(float64)
// reference ordering (round-5 absmax 3456 = fp32 summation-order near-tie
// swaps; fp64 noise 1e-13 vs rank gaps ~0.13 kills them). Also emits bf16
// P=[M1|-M2], Q=[M2|M1] (row-major, K=128) for the MFMA filter:
// P_i . Q_j = M1_i.M2_j - M2_i.M1_j.
__global__ __launch_bounds__(256) void k_mlp(const float* __restrict__ x,
                                             const float* __restrict__ W1,
                                             const float* __restrict__ b1,
                                             const float* __restrict__ W2,
                                             const float* __restrict__ b2,
                                             const float* __restrict__ M1,
                                             double* __restrict__ M2d,
                                             __hip_bfloat16* __restrict__ Pb,
                                             __hip_bfloat16* __restrict__ Qb)
{
    const int n    = blockIdx.x * 4 + (threadIdx.x >> 6);
    const int lane = threadIdx.x & 63;

    const double xv  = (double)x[n * FF + lane];
    double hacc      = (double)b1[n * HH + lane];
    const float* w1  = W1 + (size_t)n * FF * HH;
#pragma unroll
    for (int f = 0; f < FF; ++f)
        hacc = fma(__shfl(xv, f, 64), (double)w1[f * HH + lane], hacc);
    const double hv = fmax(hacc, 0.0);

    double macc     = (double)b2[n * DD + lane];
    const float* w2 = W2 + (size_t)n * HH * DD;
#pragma unroll
    for (int h = 0; h < HH; ++h)
        macc = fma(__shfl(hv, h, 64), (double)w2[h * DD + lane], macc);

    M2d[(size_t)n * DD + lane] = macc;
    const float mf  = (float)macc;
    const float m1v = M1[(size_t)n * DD + lane];
    Pb[(size_t)n * 128 + lane]      = __float2bfloat16(m1v);
    Pb[(size_t)n * 128 + 64 + lane] = __float2bfloat16(-mf);
    Qb[(size_t)n * 128 + lane]      = __float2bfloat16(mf);
    Qb[(size_t)n * 128 + 64 + lane] = __float2bfloat16(m1v);
}

// K2: bf16 MFMA score tiles + per-chunk approx top-PCK + zero-fill of A_masked
// slice. Filter margins: bf16 dot noise sigma~0.06 vs chunk-exclusion margin
// (needs 20 items above global rank-15 level in a lambda~1 Poisson cell,
// P~1e-19) and merge margin ~18 sigma (P~1e-72) -> candidate loss ~0.
// C frag (verified m89/m91): col = lane&15, row = (lane>>4)*4 + reg.
__global__ __launch_bounds__(64, 2) void k_score(const __hip_bfloat16* __restrict__ Pb,
                                                 const __hip_bfloat16* __restrict__ Qb,
                                                 float* __restrict__ cv,
                                                 int* __restrict__ ci,
                                                 float* __restrict__ outA)
{
    __shared__ float Cs[64][68];   // +4 pad: b128 reads 16B-aligned, conflicts <= 4-way
    const int ch = blockIdx.x, rb = blockIdx.y, lane = threadIdx.x;
    const int rlo = lane & 15;
    const int khi = (lane >> 4) * 8;

    bf16x8 a[4][4];
#pragma unroll
    for (int rf = 0; rf < 4; ++rf)
#pragma unroll
        for (int ks = 0; ks < 4; ++ks)
            a[rf][ks] = *(const bf16x8*)(Pb + (size_t)(rb * 64 + rf * 16 + rlo) * 128 + ks * 32 + khi);

    float tv[PCK]; int ti[PCK];
#pragma unroll
    for (int k = 0; k < PCK; ++k) { tv[k] = -1.0f; ti[k] = 0x7fffffff; }

    for (int t = 0; t < CTILES; ++t) {
        const int c0 = ch * CCOLS + t * 64;

        f32x4 acc[4][4];
#pragma unroll
        for (int rf = 0; rf < 4; ++rf)
#pragma unroll
            for (int cf = 0; cf < 4; ++cf)
                acc[rf][cf] = (f32x4){0.0f, 0.0f, 0.0f, 0.0f};

#pragma unroll
        for (int ks = 0; ks < 4; ++ks) {
            bf16x8 b[4];
#pragma unroll
            for (int cf = 0; cf < 4; ++cf)
                b[cf] = *(const bf16x8*)(Qb + (size_t)(c0 + cf * 16 + rlo) * 128 + ks * 32 + khi);
#pragma unroll
            for (int rf = 0; rf < 4; ++rf)
#pragma unroll
                for (int cf = 0; cf < 4; ++cf)
                    acc[rf][cf] = __builtin_amdgcn_mfma_f32_16x16x32_bf16(a[rf][ks], b[cf], acc[rf][cf], 0, 0, 0);
        }

        __syncthreads();
#pragma unroll
        for (int rf = 0; rf < 4; ++rf)
#pragma unroll
            for (int cf = 0; cf < 4; ++cf)
#pragma unroll
                for (int r = 0; r < 4; ++r)
                    Cs[rf * 16 + (lane >> 4) * 4 + r][cf * 16 + rlo] = acc[rf][cf][r];
        __syncthreads();

        const f32x4* crow = (const f32x4*)(&Cs[lane][0]);
#pragma unroll
        for (int c4 = 0; c4 < 16; ++c4) {
            f32x4 v4 = crow[c4];
#pragma unroll
            for (int e = 0; e < 4; ++e) {
                float v = fmaxf(v4[e], 0.0f);
                int j = c0 + c4 * 4 + e;
                if ((v > tv[PCK - 1]) || (v == tv[PCK - 1] && j < ti[PCK - 1]))
                    topk_insert<PCK>(tv, ti, v, j);
            }
        }

        // zero-fill this block's A_masked tile (fp32): 256 B per lane-row
        f32x4* az = (f32x4*)(outA + (size_t)(rb * 64 + lane) * NN + c0);
        const f32x4 z4 = {0.0f, 0.0f, 0.0f, 0.0f};
#pragma unroll
        for (int i = 0; i < 16; ++i) az[i] = z4;
    }

    const int row = rb * 64 + lane;
#pragma unroll
    for (int k = 0; k < PCK; ++k) {
        cv[(size_t)(ch * PCK + k) * NN + row] = tv[k];
        ci[(size_t)(ch * PCK + k) * NN + row] = ti[k];
    }
}

// K3: per-row merge of CHUNKS*PCK approx candidates -> RK candidate indices.
__global__ __launch_bounds__(256) void k_merge(const float* __restrict__ cv,
                                               const int* __restrict__ ci,
                                               int* __restrict__ cand)
{
    const int row = blockIdx.x * 256 + threadIdx.x;
    float tv[RK]; int ti[RK];
#pragma unroll
    for (int k = 0; k < RK; ++k) { tv[k] = -1.0f; ti[k] = 0x7fffffff; }
    for (int c = 0; c < CHUNKS * PCK; ++c) {
        float v = cv[(size_t)c * NN + row];
        int   j = ci[(size_t)c * NN + row];
        if ((v > tv[RK - 1]) || (v == tv[RK - 1] && j < ti[RK - 1]))
            topk_insert<RK>(tv, ti, v, j);
    }
#pragma unroll
    for (int k = 0; k < RK; ++k) cand[row * RK + k] = ti[k];
}

// K4: EXACT FP64 rescore of RK candidates per row (wave per row), fp64 top-15,
// emit edge list + scatter into pre-zeroed A_masked.
// d_out = ONE flat float32 buffer (confirmed rounds 2/4/5); indices written as
// float VALUES. FP64 makes the selected ordering summation-order-independent
// (delta ~1e-13 vs rank gaps ~0.13) so it matches the harness np reference.
__global__ __launch_bounds__(256) void k_final(const float* __restrict__ M1,
                                               const double* __restrict__ M2d,
                                               const int* __restrict__ cand,
                                               float* __restrict__ out_idx,
                                               float* __restrict__ out_attr,
                                               float* __restrict__ outA)
{
    const int row  = blockIdx.x * 4 + (threadIdx.x >> 6);
    const int lane = threadIdx.x & 63;
    const double m1i = (double)M1[(size_t)row * DD + lane];
    const double m2i = M2d[(size_t)row * DD + lane];

    double tv[TOPK]; int ti[TOPK];
#pragma unroll
    for (int k = 0; k < TOPK; ++k) { tv[k] = -1.0; ti[k] = 0x7fffffff; }

    for (int k = 0; k < RK; ++k) {
        const int j = cand[row * RK + k] & (NN - 1);   // wave-uniform, in-bounds
        double t1 = m1i * M2d[(size_t)j * DD + lane];  // M1_i . M2_j
        double t2 = m2i * (double)M1[(size_t)j * DD + lane];  // M2_i . M1_j
#pragma unroll
        for (int off = 32; off > 0; off >>= 1) {
            t1 += __shfl_xor(t1, off, 64);
            t2 += __shfl_xor(t2, off, 64);
        }
        double v = fmax(t1 - t2, 0.0);
        if ((v > tv[TOPK - 1]) || (v == tv[TOPK - 1] && j < ti[TOPK - 1]))
            topk_insert<TOPK>(tv, ti, v, j);
    }

    if (lane == 0) {
        const size_t base = (size_t)row * TOPK;
#pragma unroll
        for (int k = 0; k < TOPK; ++k) {
            float v = (float)tv[k];
            out_idx[base + k]                     = (float)row;    // src as value
            out_idx[(size_t)NN * TOPK + base + k] = (float)ti[k];  // dst as value
            out_attr[base + k]                    = v;
            outA[(size_t)row * NN + (ti[k] & (NN - 1))] = v;
        }
    }
}

extern "C" void kernel_launch(void* const* d_in, const int* in_sizes, int n_in,
                              void* d_out, int out_size, void* d_ws, size_t ws_size,
                              hipStream_t stream)
{
    const float* x  = (const float*)d_in[0];
    const float* W1 = (const float*)d_in[1];
    const float* b1 = (const float*)d_in[2];
    const float* W2 = (const float*)d_in[3];
    const float* b2 = (const float*)d_in[4];
    const float* M1 = (const float*)d_in[5];   // prev_embed

    char* ws = (char*)d_ws;                                    // ~30.1 MB used
    double*         M2d  = (double*)(ws);                      // 4 MB
    __hip_bfloat16* Pb   = (__hip_bfloat16*)(ws + 4194304);    // 2 MB
    __hip_bfloat16* Qb   = (__hip_bfloat16*)(ws + 6291456);    // 2 MB
    float*          cv   = (float*)(ws + 8388608);             // 10.49 MB
    int*            ci   = (int*)  (ws + 18874368);            // 10.49 MB
    int*            cand = (int*)  (ws + 29360128);            // 0.79 MB

    // d_out: flat float32, outputs concatenated in return order.
    float* out_idx  = (float*)d_out;                      // [2, N*TOPK] as float values
    float* out_attr = (float*)d_out + 2 * NN * TOPK;      // [N*TOPK]
    float* outA     = (float*)d_out + 3 * NN * TOPK;      // [N, N]

    hipLaunchKernelGGL(k_mlp,   dim3(NN / 4),          dim3(256), 0, stream,
                       x, W1, b1, W2, b2, M1, M2d, Pb, Qb);
    hipLaunchKernelGGL(k_score, dim3(CHUNKS, NN / 64), dim3(64),  0, stream,
                       Pb, Qb, cv, ci, outA);
    hipLaunchKernelGGL(k_merge, dim3(NN / 256),        dim3(256), 0, stream,
                       cv, ci, cand);
    hipLaunchKernelGGL(k_final, dim3(NN / 4),          dim3(256), 0, stream,
                       M1, M2d, cand, out_idx, out_attr, outA);
}